// Round 1
// baseline (1557.408 us; speedup 1.0000x reference)
//
#include <hip/hip_runtime.h>

#define DD 32

// ---- degree: deg[dst] += 1 --------------------------------------------------
__global__ void k_deg(const int* __restrict__ dst, int E, float* __restrict__ deg) {
    int i = blockIdx.x * blockDim.x + threadIdx.x;
    if (i < E) atomicAdd(&deg[dst[i]], 1.0f);
}

// ---- scatter-add: acc[dst[e]][d] += x[src[e]][d] ----------------------------
// one thread per (edge, feature); 32 lanes cover one edge's contiguous 128B row
__global__ void k_scatter(const float* __restrict__ x, const int* __restrict__ src,
                          const int* __restrict__ dst, int E, float* __restrict__ acc) {
    long long t = (long long)blockIdx.x * blockDim.x + threadIdx.x;
    int e = (int)(t >> 5);
    int d = (int)(t & 31);
    if (e < E) {
        int s = src[e], v = dst[e];
        atomicAdd(&acc[(long long)v * DD + d], x[(long long)s * DD + d]);
    }
}

// ---- node transform: out[v] = relu?( x[v]@Ws^T + b + (acc[v]/max(deg,1))@Wn^T )
// 256 threads = 8 nodes/block, 32 threads per node (thread d -> out feature d).
// W stored transposed in LDS so the inner loop reads WsT[k*32+d] conflict-free.
__global__ void k_node(const float* __restrict__ xdst, const float* __restrict__ acc,
                       const float* __restrict__ deg,
                       const float* __restrict__ Ws, const float* __restrict__ Wn,
                       const float* __restrict__ b,
                       float* __restrict__ out, int n, int do_relu) {
    __shared__ float WsT[DD * DD], WnT[DD * DD], bsh[DD];
    __shared__ float xrow[8][DD], mrow[8][DD];
    int tid = threadIdx.x;
    for (int i = tid; i < DD * DD; i += blockDim.x) {
        int r = i / DD, c = i % DD;
        WsT[c * DD + r] = Ws[i];
        WnT[c * DD + r] = Wn[i];
    }
    if (tid < DD) bsh[tid] = b[tid];
    int g = tid >> 5;          // node slot within block
    int d = tid & 31;          // output feature
    int v = blockIdx.x * 8 + g;
    if (v < n) {
        float dg = deg[v];
        float rinv = 1.0f / fmaxf(dg, 1.0f);
        xrow[g][d] = xdst[(long long)v * DD + d];
        mrow[g][d] = acc[(long long)v * DD + d] * rinv;
    }
    __syncthreads();
    if (v < n) {
        float s = 0.f;
#pragma unroll
        for (int k = 0; k < DD; ++k) {
            s += xrow[g][k] * WsT[k * DD + d];
            s += mrow[g][k] * WnT[k * DD + d];
        }
        s += bsh[d];
        if (do_relu) s = fmaxf(s, 0.f);
        out[(long long)v * DD + d] = s;
    }
}

extern "C" void kernel_launch(void* const* d_in, const int* in_sizes, int n_in,
                              void* d_out, int out_size, void* d_ws, size_t ws_size,
                              hipStream_t stream) {
    const float* x_user = (const float*)d_in[0];
    const float* x_item = (const float*)d_in[1];
    const int*   ui_src = (const int*)d_in[2];
    const int*   ui_dst = (const int*)d_in[3];
    const int*   iu_src = (const int*)d_in[4];
    const int*   iu_dst = (const int*)d_in[5];
    const float* Ws_ui1 = (const float*)d_in[6];
    const float* Wn_ui1 = (const float*)d_in[7];
    const float* Ws_iu1 = (const float*)d_in[8];
    const float* Wn_iu1 = (const float*)d_in[9];
    const float* Ws_ui2 = (const float*)d_in[10];
    const float* Wn_ui2 = (const float*)d_in[11];
    const float* Ws_iu2 = (const float*)d_in[12];
    const float* Wn_iu2 = (const float*)d_in[13];
    const float* b_ui1  = (const float*)d_in[14];
    const float* b_iu1  = (const float*)d_in[15];
    const float* b_ui2  = (const float*)d_in[16];
    const float* b_iu2  = (const float*)d_in[17];

    int NU = in_sizes[0] / DD;
    int NI = in_sizes[1] / DD;
    int E  = in_sizes[2];

    // workspace layout: acc_item | acc_user | deg_item | deg_user
    float* acc_item = (float*)d_ws;
    float* acc_user = acc_item + (size_t)NI * DD;
    float* deg_item = acc_user + (size_t)NU * DD;
    float* deg_user = deg_item + NI;

    // layer-1 hidden states live in d_out (o_user slot first, then o_item);
    // layer-2 node kernel updates them in place after the scatters consumed them
    float* h_user = (float*)d_out;
    float* h_item = h_user + (size_t)NU * DD;

    size_t zero_bytes = ((size_t)(NI + NU) * DD + (size_t)NI + NU) * sizeof(float);
    hipMemsetAsync(d_ws, 0, zero_bytes, stream);

    const int tb = 256;
    int degGrid = (E + tb - 1) / tb;
    hipLaunchKernelGGL(k_deg, dim3(degGrid), dim3(tb), 0, stream, ui_dst, E, deg_item);
    hipLaunchKernelGGL(k_deg, dim3(degGrid), dim3(tb), 0, stream, iu_dst, E, deg_user);

    long long sthreads = (long long)E * DD;
    int sgrid = (int)((sthreads + tb - 1) / tb);

    // ---- layer 1 aggregation ----
    hipLaunchKernelGGL(k_scatter, dim3(sgrid), dim3(tb), 0, stream, x_user, ui_src, ui_dst, E, acc_item);
    hipLaunchKernelGGL(k_scatter, dim3(sgrid), dim3(tb), 0, stream, x_item, iu_src, iu_dst, E, acc_user);

    // ---- layer 1 node transform (relu) ----
    hipLaunchKernelGGL(k_node, dim3((NI + 7) / 8), dim3(tb), 0, stream,
                       x_item, acc_item, deg_item, Ws_ui1, Wn_ui1, b_ui1, h_item, NI, 1);
    hipLaunchKernelGGL(k_node, dim3((NU + 7) / 8), dim3(tb), 0, stream,
                       x_user, acc_user, deg_user, Ws_iu1, Wn_iu1, b_iu1, h_user, NU, 1);

    // ---- layer 2 aggregation ----
    hipMemsetAsync(d_ws, 0, (size_t)(NI + NU) * DD * sizeof(float), stream);
    hipLaunchKernelGGL(k_scatter, dim3(sgrid), dim3(tb), 0, stream, h_user, ui_src, ui_dst, E, acc_item);
    hipLaunchKernelGGL(k_scatter, dim3(sgrid), dim3(tb), 0, stream, h_item, iu_src, iu_dst, E, acc_user);

    // ---- layer 2 node transform (no relu), in place over h ----
    hipLaunchKernelGGL(k_node, dim3((NI + 7) / 8), dim3(tb), 0, stream,
                       h_item, acc_item, deg_item, Ws_ui2, Wn_ui2, b_ui2, h_item, NI, 0);
    hipLaunchKernelGGL(k_node, dim3((NU + 7) / 8), dim3(tb), 0, stream,
                       h_user, acc_user, deg_user, Ws_iu2, Wn_iu2, b_iu2, h_user, NU, 0);
}